// Round 3
// baseline (560.085 us; speedup 1.0000x reference)
//
#include <hip/hip_runtime.h>
#include <stdint.h>

#define B_ 8
#define T_ 4096
#define D_ 1024
#define H_ 8
#define BW_ 128
#define NC_ 32
#define CT_ 128
#define EPS7 1e-7f
#define EPS5 1e-5f
#define LOG1MEPS -1.0000186e-05f   // log(1 - 1e-5)

typedef _Float16 f16x8 __attribute__((ext_vector_type(8)));
typedef float f32x4 __attribute__((ext_vector_type(4)));

// pack normed_x (f16) in low half, (1 - a) (f16) in high half.
// 1-a in [1e-5, 0.049] -> f16 ulp <= 2^-16, log-a error ~8e-6/step.
__device__ __forceinline__ uint32_t pack_anx(float a, float nx) {
  const unsigned short lo = __builtin_bit_cast(unsigned short, (_Float16)nx);
  const unsigned short hi = __builtin_bit_cast(unsigned short, (_Float16)(1.0f - a));
  return (uint32_t)lo | ((uint32_t)hi << 16);
}
__device__ __forceinline__ void unpack_anx(uint32_t v, float& a, float& u) {
  const _Float16 lo = __builtin_bit_cast(_Float16, (unsigned short)(v & 0xffffu));
  const _Float16 hi = __builtin_bit_cast(_Float16, (unsigned short)(v >> 16));
  u = (float)lo + EPS7;
  a = 1.0f - (float)hi;
}
__device__ __forceinline__ float unpack_a(uint32_t v) {
  const _Float16 hi = __builtin_bit_cast(_Float16, (unsigned short)(v >> 16));
  return 1.0f - (float)hi;
}

// ---------------------------------------------------------------------------
// K1: block (b, head, 128-row chunk). MFMA f16 gate matmuls, two j-tile
// passes to keep live VGPRs low (weights 32 + af 16 + acc 8). Epilogue per
// m-tile. Writes packed (nx, 1-a) -> P, per-chunk sum log(a) -> CS.
// ---------------------------------------------------------------------------
__global__ __launch_bounds__(256, 4) void k1_gates(
    const float* __restrict__ x, const float* __restrict__ a_param,
    const float* __restrict__ w_in, const float* __restrict__ b_in,
    const float* __restrict__ w_a, const float* __restrict__ b_a,
    uint32_t* __restrict__ P, float* __restrict__ CS)
{
  const int bid  = blockIdx.x;
  const int kc   = bid & (NC_ - 1);
  const int h    = (bid >> 5) & (H_ - 1);
  const int b    = bid >> 8;
  const int tid  = threadIdx.x;
  const int wave = tid >> 6;
  const int lane = tid & 63;
  const int quad = lane >> 4;
  const int l15  = lane & 15;

  __shared__ _Float16 xs[128 * 136];   // stride 136 f16 = 68 dw: b128 conflict-free

  const float* xg = x + (size_t)(b * T_ + kc * CT_) * D_ + h * BW_;
  const int jc = wave * 32;

  // --- stage x -> LDS f16, one row per thread (f16x8 stores, conflict-free) ---
  {
    const int row   = tid & 127;
    const int halfc = (tid >> 7) * 64;
    const float*  xr = xg + (size_t)row * D_ + halfc;
    _Float16*     xw = xs + row * 136 + halfc;
    #pragma unroll
    for (int i = 0; i < 8; ++i) {
      const float4 v0 = *(const float4*)(xr + i * 8);
      const float4 v1 = *(const float4*)(xr + i * 8 + 4);
      f16x8 hv = { (_Float16)v0.x, (_Float16)v0.y, (_Float16)v0.z, (_Float16)v0.w,
                   (_Float16)v1.x, (_Float16)v1.y, (_Float16)v1.z, (_Float16)v1.w };
      *(f16x8*)(xw + i * 8) = hv;
    }
  }
  __syncthreads();

  float sla[2] = {0.f, 0.f};
  const size_t obase = (size_t)(b * T_ + kc * CT_) * D_ + h * BW_;

  for (int jt = 0; jt < 2; ++jt) {
    const int col = jc + jt * 16 + l15;
    const int jg  = h * BW_ + col;

    // B fragments for this j-tile only (one-time, L2-hot)
    f16x8 bf[2][4];
    #pragma unroll
    for (int g = 0; g < 2; ++g) {
      const float* wptr = (g ? w_a : w_in) + h * BW_ * BW_ + col;
      #pragma unroll
      for (int k = 0; k < 4; ++k) {
        const float* wp = wptr + (k * 32 + quad * 8) * BW_;
        f16x8 f;
        #pragma unroll
        for (int i = 0; i < 8; ++i) f[i] = (_Float16)wp[i * BW_];
        bf[g][k] = f;
      }
    }
    const float bI = b_in[jg];
    const float bA = b_a[jg];
    const float ap = a_param[jg];
    const float cdec = ((ap > 20.f) ? ap : log1pf(__expf(ap))) + 0.001f;

    #pragma unroll
    for (int m = 0; m < 8; ++m) {
      f16x8 af[4];
      #pragma unroll
      for (int k = 0; k < 4; ++k)
        af[k] = *(const f16x8*)(xs + (m * 16 + l15) * 136 + k * 32 + quad * 8);
      f32x4 accI = {0.f, 0.f, 0.f, 0.f}, accA = {0.f, 0.f, 0.f, 0.f};
      #pragma unroll
      for (int k = 0; k < 4; ++k) {
        accI = __builtin_amdgcn_mfma_f32_16x16x32_f16(af[k], bf[0][k], accI, 0, 0, 0);
        accA = __builtin_amdgcn_mfma_f32_16x16x32_f16(af[k], bf[1][k], accA, 0, 0, 0);
      }
      // D layout: col = l15, row = m*16 + quad*4 + r
      #pragma unroll
      for (int r = 0; r < 4; ++r) {
        const int row = m * 16 + quad * 4 + r;
        const float yi = accI[r] + bI;
        const float ya = accA[r] + bA;
        const float gx = __builtin_amdgcn_rcpf(1.f + __expf(-yi));
        const float ga = __builtin_amdgcn_rcpf(1.f + __expf(-ya));
        const float la = -ga * cdec;
        const float a  = fminf(__expf(la), 1.0f - EPS5);
        const float mult = sqrtf(fmaxf(fmaf(-a, a, 1.0f), EPS5));
        const float xv = (float)xs[row * 136 + col];
        const float nx = xv * gx * mult;
        P[obase + (size_t)row * D_ + col] = pack_anx(a, nx);
        sla[jt] += fminf(la, LOG1MEPS);
      }
    }
  }
  // reduce log-a sums across quads (rows partitioned by quad), emit CS
  #pragma unroll
  for (int jt = 0; jt < 2; ++jt) {
    sla[jt] += __shfl_xor(sla[jt], 16, 64);
    sla[jt] += __shfl_xor(sla[jt], 32, 64);
  }
  if (quad == 0) {
    const int cs = (b * NC_ + kc) * D_ + h * BW_ + jc;
    CS[cs + l15]      = sla[0];
    CS[cs + 16 + l15] = sla[1];
  }
}

// ---------------------------------------------------------------------------
// K2: in-place exclusive prefix over chunk log-sums (CS -> log q at starts).
// ---------------------------------------------------------------------------
__global__ __launch_bounds__(256) void k2_scan_logs(float* __restrict__ CS)
{
  const int idx = blockIdx.x * 256 + threadIdx.x;   // B_*D_ threads
  const int b = idx >> 10;
  const int d = idx & (D_ - 1);
  float lq = 0.f;
  #pragma unroll
  for (int kk = 0; kk < NC_; ++kk) {
    const int o = (b * NC_ + kk) * D_ + d;
    const float c = CS[o];
    CS[o] = lq;
    lq += c;
  }
}

// per-step decay. State: c = q_{t-1}, pp = p_{t-1}, aprev = a_{t-1}
__device__ __forceinline__ float scan_r(float c, float pp, float aprev) {
  return (c > EPS7) ? aprev
                    : ((pp > EPS7) ? (EPS7 * __builtin_amdgcn_rcpf(pp)) : 1.0f);
}

// ---------------------------------------------------------------------------
// K3a: per-chunk linear composition summary (A = prod r, B = local scan end).
// Packed input, 8-step register prefetch.
// ---------------------------------------------------------------------------
__global__ __launch_bounds__(256) void k3_summary(
    const uint32_t* __restrict__ P, const float* __restrict__ LQ,
    float* __restrict__ Ak, float* __restrict__ Bk)
{
  const int bid = blockIdx.x;
  const int g = bid & 3;
  const int k = (bid >> 2) & (NC_ - 1);
  const int b = bid >> 7;
  const int d = g * 256 + threadIdx.x;
  const size_t base = (size_t)(b * T_ + k * CT_) * D_ + d;

  float c, pp, aprev;
  if (k == 0) { c = 1.f; pp = 1.f; aprev = 1.f; }
  else {
    c = __expf(LQ[(b * NC_ + k) * D_ + d]);
    aprev = unpack_a(P[base - D_]);
    pp = fmaxf(c / aprev, EPS7);
  }
  uint32_t cur[8];
  #pragma unroll
  for (int i = 0; i < 8; ++i) cur[i] = P[base + (size_t)i * D_];

  float hv = 0.f, rp = 1.f;
  for (int t = 0; t < CT_; t += 8) {
    const int tn = (t + 8 < CT_) ? (t + 8) : t;   // last iter: dummy L1-hot refetch
    uint32_t nxt[8];
    #pragma unroll
    for (int i = 0; i < 8; ++i) nxt[i] = P[base + (size_t)(tn + i) * D_];
    #pragma unroll
    for (int i = 0; i < 8; ++i) {
      float av, uv; unpack_anx(cur[i], av, uv);
      const float p = fmaxf(c, EPS7);
      const float r = scan_r(c, pp, aprev);
      hv = fmaf(r, hv, uv);
      rp *= r;
      c *= av; pp = p; aprev = av;
    }
    #pragma unroll
    for (int i = 0; i < 8; ++i) cur[i] = nxt[i];
  }
  Ak[(b * NC_ + k) * D_ + d] = rp;
  Bk[(b * NC_ + k) * D_ + d] = hv;
}

// ---------------------------------------------------------------------------
// K3b: chain chunk summaries -> h carry-in per chunk (in place: Ak -> Hc).
// ---------------------------------------------------------------------------
__global__ __launch_bounds__(256) void k3_carry(
    float* __restrict__ Ak, const float* __restrict__ Bk)
{
  const int idx = blockIdx.x * 256 + threadIdx.x;
  const int b = idx >> 10;
  const int d = idx & (D_ - 1);
  float Hv = 0.f;
  #pragma unroll
  for (int kk = 0; kk < NC_; ++kk) {
    const int o = (b * NC_ + kk) * D_ + d;
    const float Av = Ak[o];
    Ak[o] = Hv;
    Hv = fmaf(Av, Hv, Bk[o]);
  }
}

// ---------------------------------------------------------------------------
// K3c: seeded full scan; packed input, prefetched; writes h (fp32) to out.
// ---------------------------------------------------------------------------
__global__ __launch_bounds__(256) void k3_scan(
    const uint32_t* __restrict__ P, const float* __restrict__ LQ,
    const float* __restrict__ Hc, float* __restrict__ out)
{
  const int bid = blockIdx.x;
  const int g = bid & 3;
  const int k = (bid >> 2) & (NC_ - 1);
  const int b = bid >> 7;
  const int d = g * 256 + threadIdx.x;
  const size_t base = (size_t)(b * T_ + k * CT_) * D_ + d;

  float c, pp, aprev;
  if (k == 0) { c = 1.f; pp = 1.f; aprev = 1.f; }
  else {
    c = __expf(LQ[(b * NC_ + k) * D_ + d]);
    aprev = unpack_a(P[base - D_]);
    pp = fmaxf(c / aprev, EPS7);
  }
  uint32_t cur[8];
  #pragma unroll
  for (int i = 0; i < 8; ++i) cur[i] = P[base + (size_t)i * D_];

  float hv = Hc[(b * NC_ + k) * D_ + d];
  for (int t = 0; t < CT_; t += 8) {
    const int tn = (t + 8 < CT_) ? (t + 8) : t;
    uint32_t nxt[8];
    #pragma unroll
    for (int i = 0; i < 8; ++i) nxt[i] = P[base + (size_t)(tn + i) * D_];
    #pragma unroll
    for (int i = 0; i < 8; ++i) {
      float av, uv; unpack_anx(cur[i], av, uv);
      const float p = fmaxf(c, EPS7);
      const float r = scan_r(c, pp, aprev);
      hv = fmaf(r, hv, uv);
      out[base + (size_t)(t + i) * D_] = hv;
      c *= av; pp = p; aprev = av;
    }
    #pragma unroll
    for (int i = 0; i < 8; ++i) cur[i] = nxt[i];
  }
}

extern "C" void kernel_launch(void* const* d_in, const int* in_sizes, int n_in,
                              void* d_out, int out_size, void* d_ws, size_t ws_size,
                              hipStream_t stream) {
  const float* x       = (const float*)d_in[0];
  const float* a_param = (const float*)d_in[1];
  const float* w_in    = (const float*)d_in[2];
  const float* b_in    = (const float*)d_in[3];
  const float* w_a     = (const float*)d_in[4];
  const float* b_a     = (const float*)d_in[5];
  float* out = (float*)d_out;

  char* ws = (char*)d_ws;
  uint32_t* P  = (uint32_t*)ws;                              // B*T*D u32 = 128 MiB
  float*    CS = (float*)(ws + (size_t)B_ * T_ * D_ * 4);    // 1 MiB (-> LQ)
  float*    Ak = CS + B_ * NC_ * D_;                         // 1 MiB (-> Hc)
  float*    Bk = Ak + B_ * NC_ * D_;                         // 1 MiB

  k1_gates<<<B_ * H_ * NC_, 256, 0, stream>>>(x, a_param, w_in, b_in, w_a, b_a,
                                              P, CS);
  k2_scan_logs<<<(B_ * D_) / 256, 256, 0, stream>>>(CS);
  k3_summary<<<B_ * NC_ * (D_ / 256), 256, 0, stream>>>(P, CS, Ak, Bk);
  k3_carry<<<(B_ * D_) / 256, 256, 0, stream>>>(Ak, Bk);
  k3_scan<<<B_ * NC_ * (D_ / 256), 256, 0, stream>>>(P, CS, Ak, out);
}